// Round 10
// baseline (391.765 us; speedup 1.0000x reference)
//
#include <hip/hip_runtime.h>
#include <stdint.h>
#include <math.h>

// MixtureOfDepths: B=4, L=4096, D=1024, Dff=4096, capacity 0.5 -> k=2048.
// R14 -> R15: two low-risk trims on the proven R14 base (327.4us).
//  (1) gemm core: staging issue hoisted to window TOP (before the 12
//      fragment ds_reads) -- 4 VMEM loads fly ~150cy earlier, more slack
//      vs loaded-L3 latency at the window-end counted vmcnt. Hazard ledger
//      unchanged (overwrite still >=2 barriers after last reader; exactly
//      4 loads precede the vmcnt(4)).
//  (2) topk: two-level shfl scans (wave-local scan + cross-wave combine):
//      256-suffix scan 16->4 syncs/pass, 1024-prefix scans 20->3 syncs.
//      Exact integer math; selection boundary (ss[j]>=kk>ss[j+1],
//      exclusive-prefix ranks) bit-identical.
// Schedule-structure note: R11/R12/R13 established that intermediate
// pipelines between this single-barrier ring and the exact m201 8-phase
// template regress (-28..-40us); at BN=256 the 4x32KB-slot LDS cap forces
// stage-distance 2, which this core already realizes with one barrier +
// counted vmcnt. Deeper pipelining requires half-tile slots whose
// cross-wave retirement proof needs a cadence not reconstructible safely.

typedef __attribute__((ext_vector_type(8))) __bf16 bf16x8;
typedef __attribute__((ext_vector_type(4))) float f32x4;

__device__ __forceinline__ void async_cp16(const __bf16* g, __bf16* l) {
    __builtin_amdgcn_global_load_lds(
        (__attribute__((address_space(1))) void*)g,
        (__attribute__((address_space(3))) void*)l,
        16, 0, 0);
}

// gelu_tanh(x) == x * sigmoid(2*0.7978845608*(x + 0.044715 x^3)), exactly.
__device__ __forceinline__ float gelu_fast(float x) {
    float u = 1.5957691216057308f * x * (1.0f + 0.044715f * x * x);
    return x / (1.0f + __expf(-u));
}

// ---------- merged: router scores + x->bf16 (blocks < NBR) and
//            weights->bf16 (blocks >= NBR) ----------
// NOTE: score math must stay bit-identical across rounds (selection boundary).
__global__ __launch_bounds__(256) void prep(
    const float* __restrict__ x, const float* __restrict__ wr,
    float* __restrict__ scores, __bf16* __restrict__ xb,
    const float* __restrict__ p0, const float* __restrict__ p1,
    const float* __restrict__ p2,
    __bf16* __restrict__ o0, __bf16* __restrict__ o1, __bf16* __restrict__ o2,
    int nbr, int c0, int c1, int c2)
{
    if ((int)blockIdx.x < nbr) {
        int wid  = (blockIdx.x * blockDim.x + threadIdx.x) >> 6;  // token id
        int lane = threadIdx.x & 63;
        const float* row = x + (size_t)wid * 1024;
        __bf16* orow = xb + (size_t)wid * 1024;
        double s = 0.0;
        #pragma unroll
        for (int it = 0; it < 2; ++it) {
            int base = it * 512 + lane * 8;
            float4 a  = *(const float4*)(row + base);
            float4 b  = *(const float4*)(row + base + 4);
            float4 wa = *(const float4*)(wr + base);
            float4 wc = *(const float4*)(wr + base + 4);
            s += (double)a.x * wa.x + (double)a.y * wa.y
               + (double)a.z * wa.z + (double)a.w * wa.w
               + (double)b.x * wc.x + (double)b.y * wc.y
               + (double)b.z * wc.z + (double)b.w * wc.w;
            bf16x8 v;
            v[0] = (__bf16)a.x; v[1] = (__bf16)a.y; v[2] = (__bf16)a.z; v[3] = (__bf16)a.w;
            v[4] = (__bf16)b.x; v[5] = (__bf16)b.y; v[6] = (__bf16)b.z; v[7] = (__bf16)b.w;
            *(bf16x8*)(orow + base) = v;
        }
        #pragma unroll
        for (int off = 32; off > 0; off >>= 1) s += __shfl_down(s, off, 64);
        if (lane == 0) scores[wid] = (float)s;
        return;
    }
    int chunk = (blockIdx.x - nbr) * 256 + threadIdx.x;
    const float* in; __bf16* out;
    if (chunk < c0)                { in = p0 + (size_t)chunk * 8;             out = o0 + (size_t)chunk * 8; }
    else if (chunk < c0 + c1)      { int c = chunk - c0;      in = p1 + (size_t)c * 8; out = o1 + (size_t)c * 8; }
    else if (chunk < c0 + c1 + c2) { int c = chunk - c0 - c1; in = p2 + (size_t)c * 8; out = o2 + (size_t)c * 8; }
    else return;
    float4 a = *(const float4*)(in);
    float4 b = *(const float4*)(in + 4);
    bf16x8 v;
    v[0] = (__bf16)a.x; v[1] = (__bf16)a.y; v[2] = (__bf16)a.z; v[3] = (__bf16)a.w;
    v[4] = (__bf16)b.x; v[5] = (__bf16)b.y; v[6] = (__bf16)b.z; v[7] = (__bf16)b.w;
    *(bf16x8*)(out) = v;
}

// ---------------- per-batch top-k via 8-bit MSB-first radix select ----------------
// Same selected set as a full descending sort with tie-break "lower index wins".
// Scans are two-level (shfl within wave + cross-wave combine) -- exact
// integer sums, selection boundary identical to the serial scan.
__global__ __launch_bounds__(1024) void topk_build(
    const float* __restrict__ scores,
    int* __restrict__ sel_rows, int* __restrict__ byp_rows)
{
    const int L = 4096, K = 2048;
    __shared__ unsigned u[4096];
    __shared__ int hist[256];
    __shared__ int ss[256];
    __shared__ int wsum[16];
    __shared__ int wtot[4];
    __shared__ unsigned s_pref;
    __shared__ int s_kk;
    int b = blockIdx.x, t = threadIdx.x;
    int lane = t & 63, wv = t >> 6;

    for (int i = t; i < L; i += 1024) {
        unsigned v = __float_as_uint(scores[b * L + i]);
        v = (v & 0x80000000u) ? ~v : (v | 0x80000000u);   // order-preserving map
        u[i] = v;
    }
    if (t == 0) { s_pref = 0; s_kk = K; }
    __syncthreads();

    for (int shift = 24; shift >= 0; shift -= 8) {
        if (t < 256) hist[t] = 0;
        __syncthreads();
        unsigned pref = s_pref;
        int kk0 = s_kk;
        for (int i = t; i < L; i += 1024) {
            unsigned v = u[i];
            bool in_set = (shift == 24) || ((v >> (shift + 8)) == pref);
            if (in_set) atomicAdd(&hist[(v >> shift) & 255], 1);
        }
        __syncthreads();
        // inclusive suffix scan of hist[256]: wave-local suffix via shfl_down
        int vsuf = 0;
        if (t < 256) {
            vsuf = hist[t];
            #pragma unroll
            for (int off = 1; off < 64; off <<= 1) {
                int o = __shfl_down(vsuf, off, 64);
                if (lane + off < 64) vsuf += o;
            }
            if (lane == 0) wtot[wv] = vsuf;   // wave total (wv in 0..3)
        }
        __syncthreads();
        if (t < 256) {
            int base = 0;
            for (int w2 = wv + 1; w2 < 4; ++w2) base += wtot[w2];
            ss[t] = vsuf + base;              // ss[t] = sum_{i>=t} hist[i]
        }
        __syncthreads();
        // unique j with ss[j] >= kk > ss[j+1]  (same bin + remainder as the
        // descending serial scan: cum at j == ss[j+1])
        if (t < 256) {
            int ssj  = ss[t];
            int ssj1 = (t < 255) ? ss[t + 1] : 0;
            if (ssj >= kk0 && ssj1 < kk0) {
                s_kk = kk0 - ssj1;
                s_pref = (pref << 8) | (unsigned)t;
            }
        }
        __syncthreads();
    }
    unsigned thr = s_pref;
    int need = s_kk;

    int base4 = t * 4;
    unsigned v0 = u[base4], v1 = u[base4+1], v2 = u[base4+2], v3 = u[base4+3];
    int eq0 = (v0 == thr), eq1 = (v1 == thr), eq2 = (v2 == thr), eq3 = (v3 == thr);

    // exclusive prefix of eq-count over 1024 threads (two-level)
    int cnt = eq0 + eq1 + eq2 + eq3;
    int inc = cnt;
    #pragma unroll
    for (int off = 1; off < 64; off <<= 1) {
        int o = __shfl_up(inc, off, 64);
        if (lane >= off) inc += o;
    }
    if (lane == 63) wsum[wv] = inc;
    __syncthreads();
    if (t < 16) {
        int w2 = wsum[t];
        #pragma unroll
        for (int off = 1; off < 16; off <<= 1) {
            int o = __shfl_up(w2, off, 64);
            if (lane >= off) w2 += o;
        }
        wsum[t] = w2;   // inclusive over wave totals
    }
    __syncthreads();
    int erun = inc - cnt + ((wv > 0) ? wsum[wv - 1] : 0);
    int sel[4];
    {
        int r = erun;
        sel[0] = (v0 > thr) || (eq0 && r < need); r += eq0;
        sel[1] = (v1 > thr) || (eq1 && r < need); r += eq1;
        sel[2] = (v2 > thr) || (eq2 && r < need); r += eq2;
        sel[3] = (v3 > thr) || (eq3 && r < need);
    }
    __syncthreads();   // protect wsum before reuse

    // exclusive prefix of sel-count
    int scnt = sel[0] + sel[1] + sel[2] + sel[3];
    int sinc = scnt;
    #pragma unroll
    for (int off = 1; off < 64; off <<= 1) {
        int o = __shfl_up(sinc, off, 64);
        if (lane >= off) sinc += o;
    }
    if (lane == 63) wsum[wv] = sinc;
    __syncthreads();
    if (t < 16) {
        int w2 = wsum[t];
        #pragma unroll
        for (int off = 1; off < 16; off <<= 1) {
            int o = __shfl_up(w2, off, 64);
            if (lane >= off) w2 += o;
        }
        wsum[t] = w2;
    }
    __syncthreads();
    int run = sinc - scnt + ((wv > 0) ? wsum[wv - 1] : 0);
    #pragma unroll
    for (int j = 0; j < 4; ++j) {
        int idx = base4 + j;
        if (sel[j]) { sel_rows[b * K + run] = b * L + idx; run++; }
        else        { byp_rows[b * (L - K) + (idx - run)] = b * L + idx; }
    }
}

// ======== 256xBN-tile deep-pipelined GEMM core, single-barrier window ========
// (R10 core; staging hoisted to window top.)
// 8 waves (2M x 4N), per-wave 128 x BN/4 output, BK=32, 4-slot LDS ring.
// Per window: {stage slot t+2 (2+NB gload_lds) -> 12|10 ds_read_b128 ->
// 32|16 MFMA (compiler interleaves via fine-grained lgkmcnt) -> counted
// vmcnt(2+NB) -> s_barrier}. vmcnt never 0 in steady state. Hazards: reads
// of slot t consumed (lgkmcnt) before barrier t; staging into slot (t+2)&3
// occurs >=2 barriers after window t-2's readers. Swizzle: 16B slot =
// quad ^ ((row>>1)&3), inverse applied to global source (linear gload_lds
// dest). Conflict-free (verified: SQ_LDS_BANK_CONFLICT=0).
template <int BN, bool GATHER_A, bool SCATTER_OUT, bool GELU_ACT, typename OT>
__device__ __forceinline__ void gemm256_core(
    const __bf16* __restrict__ A, const __bf16* __restrict__ W,
    OT* __restrict__ Out, const int* __restrict__ rows,
    int lda, int kBeg, int kLen, int ldo, int mt, int nt,
    __bf16* ringA, __bf16* ringB, int* rs)
{
    constexpr int BM = 256, BK = 32;
    constexpr int NB = BN / 128;      // B-staging calls per tile (2 or 1)
    constexpr int NI = BN / 64;       // ni per wave (4 or 2)
    constexpr int SA = BM * BK;       // ring slot stride (elements)
    constexpr int SB = BN * BK;
    const int tid = threadIdx.x;      // 0..511
    const int m0 = mt * BM, n0 = nt * BN;

    if (tid < BM) rs[tid] = (GATHER_A || SCATTER_OUT) ? rows[m0 + tid] : 0;
    __syncthreads();

    const int srow = tid >> 2;
    const int scol = ((tid & 3) ^ ((tid >> 3) & 3)) * 8;   // elements
    const __bf16* asrc[2]; const __bf16* bsrc[NB];
    #pragma unroll
    for (int c = 0; c < 2; ++c) {
        int lr = c * 128 + srow;
        int ar = GATHER_A ? rs[lr] : (m0 + lr);
        asrc[c] = A + (size_t)ar * lda + kBeg + scol;
    }
    #pragma unroll
    for (int c = 0; c < NB; ++c)
        bsrc[c] = W + (size_t)(n0 + c * 128 + srow) * lda + kBeg + scol;
    const int ldst = tid * 8;   // element offset of this thread's 16B

    const int NT = kLen / BK;
    #pragma unroll
    for (int t = 0; t < 2; ++t) {
        #pragma unroll
        for (int c = 0; c < 2; ++c)
            async_cp16(asrc[c] + t * BK, ringA + t * SA + c * 4096 + ldst);
        #pragma unroll
        for (int c = 0; c < NB; ++c)
            async_cp16(bsrc[c] + t * BK, ringB + t * SB + c * 4096 + ldst);
    }
    if constexpr (BN == 256) asm volatile("s_waitcnt vmcnt(4)" ::: "memory");
    else                     asm volatile("s_waitcnt vmcnt(3)" ::: "memory");
    asm volatile("s_barrier" ::: "memory");

    f32x4 acc[8][NI] = {};
    const int lane = tid & 63;
    const int wv = tid >> 6;
    const int wr = (wv >> 2) * 128;              // wave M offset
    const int wc = (wv & 3) * (BN / 4);          // wave N offset
    const int r = lane & 15, quad = lane >> 4;
    const int rdoff = (quad ^ ((r >> 1) & 3)) * 8;   // swizzled 16B slot

    for (int t = 0; t < NT; ++t) {
        const __bf16* As = ringA + (t & 3) * SA;
        const __bf16* Bs = ringB + (t & 3) * SB;
        const bool pf = (t + 2 < NT);

        // staging into slot t+2 FIRST (max latency slack before the
        // window-end counted vmcnt)
        if (pf) {
            #pragma unroll
            for (int c = 0; c < 2; ++c)
                async_cp16(asrc[c] + (t + 2) * BK,
                           ringA + ((t + 2) & 3) * SA + c * 4096 + ldst);
            #pragma unroll
            for (int c = 0; c < NB; ++c)
                async_cp16(bsrc[c] + (t + 2) * BK,
                           ringB + ((t + 2) & 3) * SB + c * 4096 + ldst);
        }
        // all fragment reads for this window
        bf16x8 af[4], ag[4], bfr[NI];
        #pragma unroll
        for (int mi = 0; mi < 4; ++mi)
            af[mi] = *(const bf16x8*)(As + (wr + mi * 16 + r) * BK + rdoff);
        #pragma unroll
        for (int ni = 0; ni < NI; ++ni)
            bfr[ni] = *(const bf16x8*)(Bs + (wc + ni * 16 + r) * BK + rdoff);
        #pragma unroll
        for (int mi = 0; mi < 4; ++mi)
            ag[mi] = *(const bf16x8*)(As + (wr + 64 + mi * 16 + r) * BK + rdoff);
        __builtin_amdgcn_s_setprio(1);
        #pragma unroll
        for (int mi = 0; mi < 4; ++mi)
            #pragma unroll
            for (int ni = 0; ni < NI; ++ni)
                acc[mi][ni] = __builtin_amdgcn_mfma_f32_16x16x32_bf16(
                    af[mi], bfr[ni], acc[mi][ni], 0, 0, 0);
        #pragma unroll
        for (int mi = 0; mi < 4; ++mi)
            #pragma unroll
            for (int ni = 0; ni < NI; ++ni)
                acc[4 + mi][ni] = __builtin_amdgcn_mfma_f32_16x16x32_bf16(
                    ag[mi], bfr[ni], acc[4 + mi][ni], 0, 0, 0);
        __builtin_amdgcn_s_setprio(0);
        // counted wait: only this window's staging may stay in flight ->
        // slot t+1 (staged at window t-1) has fully landed.
        if (pf) {
            if constexpr (BN == 256) asm volatile("s_waitcnt vmcnt(4)" ::: "memory");
            else                     asm volatile("s_waitcnt vmcnt(3)" ::: "memory");
        } else {
            asm volatile("s_waitcnt vmcnt(0)" ::: "memory");
        }
        asm volatile("s_barrier" ::: "memory");
    }

    #pragma unroll
    for (int mi = 0; mi < 8; ++mi) {
        #pragma unroll
        for (int reg = 0; reg < 4; ++reg) {
            int rowl = wr + mi * 16 + quad * 4 + reg;
            int orow = SCATTER_OUT ? rs[rowl] : (m0 + rowl);
            OT* op = Out + (size_t)orow * ldo + n0;
            #pragma unroll
            for (int ni = 0; ni < NI; ++ni) {
                float v = acc[mi][ni][reg];
                if (GELU_ACT) v = gelu_fast(v);
                op[wc + ni * 16 + r] = (OT)v;
            }
        }
    }
}

// ---- dispatch 2: 768 blocks, 1/CU, per-CU schedule ~{2 ffn1 + 1 bypass}.
//   bid < 512: ffn1 256^2 (K=1024). XCD x=bid&7 owns mt 4x..4x+3; local
//              l=bid>>3: mt=4x+((l>>3)&3), nt=(l>>5)*8+(l&7) (supertiles).
//   bid >= 512: bypass 256x128 (K=1024), dispatched last (small jobs fill
//              the final scheduling round). id=bid-512: x=id&7, v=id>>3:
//              mt=4x+(v>>3), nt=v&7.
__global__ __launch_bounds__(512, 2) void gemm_mid(
    const __bf16* __restrict__ xb, const __bf16* __restrict__ w1b,
    __bf16* __restrict__ h, const __bf16* __restrict__ wbb,
    float* __restrict__ out,
    const int* __restrict__ sel_rows, const int* __restrict__ byp_rows)
{
    __shared__ __align__(16) __bf16 ringA[4][256 * 32];
    __shared__ __align__(16) __bf16 ringB[4][256 * 32];
    __shared__ int rs[256];
    int bid = blockIdx.x;
    if (bid < 512) {
        int x = bid & 7, l = bid >> 3;
        int mt = x * 4 + ((l >> 3) & 3);
        int nt = (l >> 5) * 8 + (l & 7);
        gemm256_core<256, true, false, true, __bf16>(
            xb, w1b, h, sel_rows, 1024, 0, 1024, 4096, mt, nt,
            &ringA[0][0], &ringB[0][0], rs);
    } else {
        int id = bid - 512;
        int x = id & 7, v = id >> 3;
        int mt = x * 4 + (v >> 3);
        int nt = v & 7;
        gemm256_core<128, true, true, false, float>(
            xb, wbb, out, byp_rows, 1024, 0, 1024, 1024, mt, nt,
            &ringA[0][0], &ringB[0][0], rs);
    }
}

// ---- dispatch 3: FFN2 as 256 uniform 256x128 jobs, FULL K=4096 (no
//      split-K, no reduce pass). 1/CU, single round. XCD x owns mt
//      4x..4x+3; l=bid>>3 (0..31): mt=4x+(l>>3), nt=l&7.
//      out[sel] = h@w2^T, scatter rows. Single fp32 MFMA accumulation
//      chain over k=0..4095.
__global__ __launch_bounds__(512, 2) void gemm_ffn2(
    const __bf16* __restrict__ h, const __bf16* __restrict__ w2b,
    float* __restrict__ out, const int* __restrict__ sel_rows)
{
    __shared__ __align__(16) __bf16 ringA[4][256 * 32];
    __shared__ __align__(16) __bf16 ringB[4][128 * 32];
    __shared__ int rs[256];
    int x = blockIdx.x & 7, l = blockIdx.x >> 3;
    int mt = x * 4 + (l >> 3);
    int nt = l & 7;
    gemm256_core<128, false, true, false, float>(
        h, w2b, out, sel_rows, 4096, 0, 4096, 1024, mt, nt,
        &ringA[0][0], &ringB[0][0], rs);
}

extern "C" void kernel_launch(void* const* d_in, const int* in_sizes, int n_in,
                              void* d_out, int out_size, void* d_ws, size_t ws_size,
                              hipStream_t stream) {
    (void)in_sizes; (void)n_in; (void)out_size; (void)ws_size;
    const float* x  = (const float*)d_in[0];
    const float* wr = (const float*)d_in[1];
    const float* wb = (const float*)d_in[2];
    const float* w1 = (const float*)d_in[3];
    const float* w2 = (const float*)d_in[4];
    float* out = (float*)d_out;

    const int B = 4, L = 4096, D = 1024, DFF = 4096, KSEL = 2048;
    const int M = B * KSEL;           // 8192
    const int NTOK = B * L;           // 16384

    size_t n_x = (size_t)NTOK * D, n_wb = (size_t)D * D;
    size_t n_w1 = (size_t)DFF * D, n_w2 = (size_t)D * DFF;

    char* ws = (char*)d_ws;
    float* scores = (float*)ws;            ws += sizeof(float) * (size_t)NTOK;
    int* sel_rows = (int*)ws;              ws += sizeof(int) * (size_t)M;
    int* byp_rows = (int*)ws;              ws += sizeof(int) * (size_t)M;
    uintptr_t up = ((uintptr_t)ws + 255) & ~(uintptr_t)255;
    __bf16* xb  = (__bf16*)up;             up += 2 * n_x;
    __bf16* wbb = (__bf16*)up;             up += 2 * n_wb;
    __bf16* w1b = (__bf16*)up;             up += 2 * n_w1;
    __bf16* w2b = (__bf16*)up;             up += 2 * n_w2;
    up = (up + 255) & ~(uintptr_t)255;
    __bf16* h   = (__bf16*)up;             // 8192 x 4096 bf16 = 64 MiB

    int nbr = NTOK / 4;                              // 4096 router blocks
    int ncv = (int)((n_wb + n_w1 + n_w2) / 8 / 256); // 4608 cvt blocks
    prep<<<nbr + ncv, 256, 0, stream>>>(
        x, wr, scores, xb, wb, w1, w2, wbb, w1b, w2b,
        nbr, (int)(n_wb / 8), (int)(n_w1 / 8), (int)(n_w2 / 8));
    topk_build<<<B, 1024, 0, stream>>>(scores, sel_rows, byp_rows);

    // FFN1 (512 jobs, 256^2) + bypass (256 jobs, 256x128) -> ~2.5 jobs/CU
    gemm_mid<<<768, 512, 0, stream>>>(xb, w1b, h, wbb, out, sel_rows, byp_rows);
    // FFN2: 256 uniform 256x128 jobs, full K=4096, 1/CU, no reduce pass
    gemm_ffn2<<<256, 512, 0, stream>>>(h, w2b, out, sel_rows);
}

// Round 11
// 335.876 us; speedup vs baseline: 1.1664x; 1.1664x over previous
//
#include <hip/hip_runtime.h>
#include <stdint.h>
#include <math.h>

// MixtureOfDepths: B=4, L=4096, D=1024, Dff=4096, capacity 0.5 -> k=2048.
// R15 -> R16: REVERT the stage-first hoist (109->179us, MfmaUtil 34->19.6).
// Mechanism: global_load_lds RETURNS write LDS through the same banks the
// ds_reads use; staging issued before the fragment reads makes the 64KB of
// returns land during the 12-ds_read burst (port contention), vs landing
// under the MFMA block when staging is issued after the reads. Window
// order restored VERBATIM to the twice-measured R14 core (109.2us gemm_mid,
// 327.4us total): {12|10 ds_reads -> stage slot t+2 -> MFMA -> counted
// vmcnt(4|3) -> s_barrier}. The R15 two-level shfl topk is kept
// (correctness-verified in the R15 run; independent of the GEMM change).

typedef __attribute__((ext_vector_type(8))) __bf16 bf16x8;
typedef __attribute__((ext_vector_type(4))) float f32x4;

__device__ __forceinline__ void async_cp16(const __bf16* g, __bf16* l) {
    __builtin_amdgcn_global_load_lds(
        (__attribute__((address_space(1))) void*)g,
        (__attribute__((address_space(3))) void*)l,
        16, 0, 0);
}

// gelu_tanh(x) == x * sigmoid(2*0.7978845608*(x + 0.044715 x^3)), exactly.
__device__ __forceinline__ float gelu_fast(float x) {
    float u = 1.5957691216057308f * x * (1.0f + 0.044715f * x * x);
    return x / (1.0f + __expf(-u));
}

// ---------- merged: router scores + x->bf16 (blocks < NBR) and
//            weights->bf16 (blocks >= NBR) ----------
// NOTE: score math must stay bit-identical across rounds (selection boundary).
__global__ __launch_bounds__(256) void prep(
    const float* __restrict__ x, const float* __restrict__ wr,
    float* __restrict__ scores, __bf16* __restrict__ xb,
    const float* __restrict__ p0, const float* __restrict__ p1,
    const float* __restrict__ p2,
    __bf16* __restrict__ o0, __bf16* __restrict__ o1, __bf16* __restrict__ o2,
    int nbr, int c0, int c1, int c2)
{
    if ((int)blockIdx.x < nbr) {
        int wid  = (blockIdx.x * blockDim.x + threadIdx.x) >> 6;  // token id
        int lane = threadIdx.x & 63;
        const float* row = x + (size_t)wid * 1024;
        __bf16* orow = xb + (size_t)wid * 1024;
        double s = 0.0;
        #pragma unroll
        for (int it = 0; it < 2; ++it) {
            int base = it * 512 + lane * 8;
            float4 a  = *(const float4*)(row + base);
            float4 b  = *(const float4*)(row + base + 4);
            float4 wa = *(const float4*)(wr + base);
            float4 wc = *(const float4*)(wr + base + 4);
            s += (double)a.x * wa.x + (double)a.y * wa.y
               + (double)a.z * wa.z + (double)a.w * wa.w
               + (double)b.x * wc.x + (double)b.y * wc.y
               + (double)b.z * wc.z + (double)b.w * wc.w;
            bf16x8 v;
            v[0] = (__bf16)a.x; v[1] = (__bf16)a.y; v[2] = (__bf16)a.z; v[3] = (__bf16)a.w;
            v[4] = (__bf16)b.x; v[5] = (__bf16)b.y; v[6] = (__bf16)b.z; v[7] = (__bf16)b.w;
            *(bf16x8*)(orow + base) = v;
        }
        #pragma unroll
        for (int off = 32; off > 0; off >>= 1) s += __shfl_down(s, off, 64);
        if (lane == 0) scores[wid] = (float)s;
        return;
    }
    int chunk = (blockIdx.x - nbr) * 256 + threadIdx.x;
    const float* in; __bf16* out;
    if (chunk < c0)                { in = p0 + (size_t)chunk * 8;             out = o0 + (size_t)chunk * 8; }
    else if (chunk < c0 + c1)      { int c = chunk - c0;      in = p1 + (size_t)c * 8; out = o1 + (size_t)c * 8; }
    else if (chunk < c0 + c1 + c2) { int c = chunk - c0 - c1; in = p2 + (size_t)c * 8; out = o2 + (size_t)c * 8; }
    else return;
    float4 a = *(const float4*)(in);
    float4 b = *(const float4*)(in + 4);
    bf16x8 v;
    v[0] = (__bf16)a.x; v[1] = (__bf16)a.y; v[2] = (__bf16)a.z; v[3] = (__bf16)a.w;
    v[4] = (__bf16)b.x; v[5] = (__bf16)b.y; v[6] = (__bf16)b.z; v[7] = (__bf16)b.w;
    *(bf16x8*)(out) = v;
}

// ---------------- per-batch top-k via 8-bit MSB-first radix select ----------------
// Same selected set as a full descending sort with tie-break "lower index wins".
// Scans are two-level (shfl within wave + cross-wave combine) -- exact
// integer sums, selection boundary identical to the serial scan.
__global__ __launch_bounds__(1024) void topk_build(
    const float* __restrict__ scores,
    int* __restrict__ sel_rows, int* __restrict__ byp_rows)
{
    const int L = 4096, K = 2048;
    __shared__ unsigned u[4096];
    __shared__ int hist[256];
    __shared__ int ss[256];
    __shared__ int wsum[16];
    __shared__ int wtot[4];
    __shared__ unsigned s_pref;
    __shared__ int s_kk;
    int b = blockIdx.x, t = threadIdx.x;
    int lane = t & 63, wv = t >> 6;

    for (int i = t; i < L; i += 1024) {
        unsigned v = __float_as_uint(scores[b * L + i]);
        v = (v & 0x80000000u) ? ~v : (v | 0x80000000u);   // order-preserving map
        u[i] = v;
    }
    if (t == 0) { s_pref = 0; s_kk = K; }
    __syncthreads();

    for (int shift = 24; shift >= 0; shift -= 8) {
        if (t < 256) hist[t] = 0;
        __syncthreads();
        unsigned pref = s_pref;
        int kk0 = s_kk;
        for (int i = t; i < L; i += 1024) {
            unsigned v = u[i];
            bool in_set = (shift == 24) || ((v >> (shift + 8)) == pref);
            if (in_set) atomicAdd(&hist[(v >> shift) & 255], 1);
        }
        __syncthreads();
        // inclusive suffix scan of hist[256]: wave-local suffix via shfl_down
        int vsuf = 0;
        if (t < 256) {
            vsuf = hist[t];
            #pragma unroll
            for (int off = 1; off < 64; off <<= 1) {
                int o = __shfl_down(vsuf, off, 64);
                if (lane + off < 64) vsuf += o;
            }
            if (lane == 0) wtot[wv] = vsuf;   // wave total (wv in 0..3)
        }
        __syncthreads();
        if (t < 256) {
            int base = 0;
            for (int w2 = wv + 1; w2 < 4; ++w2) base += wtot[w2];
            ss[t] = vsuf + base;              // ss[t] = sum_{i>=t} hist[i]
        }
        __syncthreads();
        // unique j with ss[j] >= kk > ss[j+1]  (same bin + remainder as the
        // descending serial scan: cum at j == ss[j+1])
        if (t < 256) {
            int ssj  = ss[t];
            int ssj1 = (t < 255) ? ss[t + 1] : 0;
            if (ssj >= kk0 && ssj1 < kk0) {
                s_kk = kk0 - ssj1;
                s_pref = (pref << 8) | (unsigned)t;
            }
        }
        __syncthreads();
    }
    unsigned thr = s_pref;
    int need = s_kk;

    int base4 = t * 4;
    unsigned v0 = u[base4], v1 = u[base4+1], v2 = u[base4+2], v3 = u[base4+3];
    int eq0 = (v0 == thr), eq1 = (v1 == thr), eq2 = (v2 == thr), eq3 = (v3 == thr);

    // exclusive prefix of eq-count over 1024 threads (two-level)
    int cnt = eq0 + eq1 + eq2 + eq3;
    int inc = cnt;
    #pragma unroll
    for (int off = 1; off < 64; off <<= 1) {
        int o = __shfl_up(inc, off, 64);
        if (lane >= off) inc += o;
    }
    if (lane == 63) wsum[wv] = inc;
    __syncthreads();
    if (t < 16) {
        int w2 = wsum[t];
        #pragma unroll
        for (int off = 1; off < 16; off <<= 1) {
            int o = __shfl_up(w2, off, 64);
            if (lane >= off) w2 += o;
        }
        wsum[t] = w2;   // inclusive over wave totals
    }
    __syncthreads();
    int erun = inc - cnt + ((wv > 0) ? wsum[wv - 1] : 0);
    int sel[4];
    {
        int r = erun;
        sel[0] = (v0 > thr) || (eq0 && r < need); r += eq0;
        sel[1] = (v1 > thr) || (eq1 && r < need); r += eq1;
        sel[2] = (v2 > thr) || (eq2 && r < need); r += eq2;
        sel[3] = (v3 > thr) || (eq3 && r < need);
    }
    __syncthreads();   // protect wsum before reuse

    // exclusive prefix of sel-count
    int scnt = sel[0] + sel[1] + sel[2] + sel[3];
    int sinc = scnt;
    #pragma unroll
    for (int off = 1; off < 64; off <<= 1) {
        int o = __shfl_up(sinc, off, 64);
        if (lane >= off) sinc += o;
    }
    if (lane == 63) wsum[wv] = sinc;
    __syncthreads();
    if (t < 16) {
        int w2 = wsum[t];
        #pragma unroll
        for (int off = 1; off < 16; off <<= 1) {
            int o = __shfl_up(w2, off, 64);
            if (lane >= off) w2 += o;
        }
        wsum[t] = w2;
    }
    __syncthreads();
    int run = sinc - scnt + ((wv > 0) ? wsum[wv - 1] : 0);
    #pragma unroll
    for (int j = 0; j < 4; ++j) {
        int idx = base4 + j;
        if (sel[j]) { sel_rows[b * K + run] = b * L + idx; run++; }
        else        { byp_rows[b * (L - K) + (idx - run)] = b * L + idx; }
    }
}

// ======== 256xBN-tile deep-pipelined GEMM core, single-barrier window ========
// (R14 core, verbatim -- measured 109.2us gemm_mid, MfmaUtil 34%.)
// 8 waves (2M x 4N), per-wave 128 x BN/4 output, BK=32, 4-slot LDS ring.
// Per window: {12|10 ds_read_b128 -> stage slot t+2 (2+NB gload_lds) ->
// 32|16 MFMA (compiler interleaves via fine-grained lgkmcnt; staging
// returns land under the MFMA block, NOT during the ds_read burst) ->
// counted vmcnt(2+NB) -> s_barrier}. vmcnt never 0 in steady state.
// Hazards: reads of slot t consumed (lgkmcnt) before barrier t; staging
// into slot (t+2)&3 occurs >=2 barriers after window t-2's readers.
// Swizzle: 16B slot = quad ^ ((row>>1)&3), inverse applied to global
// source (linear gload_lds dest). Conflict-free (verified: 0).
template <int BN, bool GATHER_A, bool SCATTER_OUT, bool GELU_ACT, typename OT>
__device__ __forceinline__ void gemm256_core(
    const __bf16* __restrict__ A, const __bf16* __restrict__ W,
    OT* __restrict__ Out, const int* __restrict__ rows,
    int lda, int kBeg, int kLen, int ldo, int mt, int nt,
    __bf16* ringA, __bf16* ringB, int* rs)
{
    constexpr int BM = 256, BK = 32;
    constexpr int NB = BN / 128;      // B-staging calls per tile (2 or 1)
    constexpr int NI = BN / 64;       // ni per wave (4 or 2)
    constexpr int SA = BM * BK;       // ring slot stride (elements)
    constexpr int SB = BN * BK;
    const int tid = threadIdx.x;      // 0..511
    const int m0 = mt * BM, n0 = nt * BN;

    if (tid < BM) rs[tid] = (GATHER_A || SCATTER_OUT) ? rows[m0 + tid] : 0;
    __syncthreads();

    const int srow = tid >> 2;
    const int scol = ((tid & 3) ^ ((tid >> 3) & 3)) * 8;   // elements
    const __bf16* asrc[2]; const __bf16* bsrc[NB];
    #pragma unroll
    for (int c = 0; c < 2; ++c) {
        int lr = c * 128 + srow;
        int ar = GATHER_A ? rs[lr] : (m0 + lr);
        asrc[c] = A + (size_t)ar * lda + kBeg + scol;
    }
    #pragma unroll
    for (int c = 0; c < NB; ++c)
        bsrc[c] = W + (size_t)(n0 + c * 128 + srow) * lda + kBeg + scol;
    const int ldst = tid * 8;   // element offset of this thread's 16B

    const int NT = kLen / BK;
    #pragma unroll
    for (int t = 0; t < 2; ++t) {
        #pragma unroll
        for (int c = 0; c < 2; ++c)
            async_cp16(asrc[c] + t * BK, ringA + t * SA + c * 4096 + ldst);
        #pragma unroll
        for (int c = 0; c < NB; ++c)
            async_cp16(bsrc[c] + t * BK, ringB + t * SB + c * 4096 + ldst);
    }
    if constexpr (BN == 256) asm volatile("s_waitcnt vmcnt(4)" ::: "memory");
    else                     asm volatile("s_waitcnt vmcnt(3)" ::: "memory");
    asm volatile("s_barrier" ::: "memory");

    f32x4 acc[8][NI] = {};
    const int lane = tid & 63;
    const int wv = tid >> 6;
    const int wr = (wv >> 2) * 128;              // wave M offset
    const int wc = (wv & 3) * (BN / 4);          // wave N offset
    const int r = lane & 15, quad = lane >> 4;
    const int rdoff = (quad ^ ((r >> 1) & 3)) * 8;   // swizzled 16B slot

    for (int t = 0; t < NT; ++t) {
        const __bf16* As = ringA + (t & 3) * SA;
        const __bf16* Bs = ringB + (t & 3) * SB;
        const bool pf = (t + 2 < NT);

        // all fragment reads for this window, issued up front
        bf16x8 af[4], ag[4], bfr[NI];
        #pragma unroll
        for (int mi = 0; mi < 4; ++mi)
            af[mi] = *(const bf16x8*)(As + (wr + mi * 16 + r) * BK + rdoff);
        #pragma unroll
        for (int ni = 0; ni < NI; ++ni)
            bfr[ni] = *(const bf16x8*)(Bs + (wc + ni * 16 + r) * BK + rdoff);
        #pragma unroll
        for (int mi = 0; mi < 4; ++mi)
            ag[mi] = *(const bf16x8*)(As + (wr + 64 + mi * 16 + r) * BK + rdoff);
        // staging into slot t+2 (ring distance 2) -- AFTER the reads, so
        // the VMEM returns land under the MFMA block
        if (pf) {
            #pragma unroll
            for (int c = 0; c < 2; ++c)
                async_cp16(asrc[c] + (t + 2) * BK,
                           ringA + ((t + 2) & 3) * SA + c * 4096 + ldst);
            #pragma unroll
            for (int c = 0; c < NB; ++c)
                async_cp16(bsrc[c] + (t + 2) * BK,
                           ringB + ((t + 2) & 3) * SB + c * 4096 + ldst);
        }
        __builtin_amdgcn_s_setprio(1);
        #pragma unroll
        for (int mi = 0; mi < 4; ++mi)
            #pragma unroll
            for (int ni = 0; ni < NI; ++ni)
                acc[mi][ni] = __builtin_amdgcn_mfma_f32_16x16x32_bf16(
                    af[mi], bfr[ni], acc[mi][ni], 0, 0, 0);
        #pragma unroll
        for (int mi = 0; mi < 4; ++mi)
            #pragma unroll
            for (int ni = 0; ni < NI; ++ni)
                acc[4 + mi][ni] = __builtin_amdgcn_mfma_f32_16x16x32_bf16(
                    ag[mi], bfr[ni], acc[4 + mi][ni], 0, 0, 0);
        __builtin_amdgcn_s_setprio(0);
        // counted wait: only this window's staging may stay in flight ->
        // slot t+1 (staged at window t-1) has fully landed.
        if (pf) {
            if constexpr (BN == 256) asm volatile("s_waitcnt vmcnt(4)" ::: "memory");
            else                     asm volatile("s_waitcnt vmcnt(3)" ::: "memory");
        } else {
            asm volatile("s_waitcnt vmcnt(0)" ::: "memory");
        }
        asm volatile("s_barrier" ::: "memory");
    }

    #pragma unroll
    for (int mi = 0; mi < 8; ++mi) {
        #pragma unroll
        for (int reg = 0; reg < 4; ++reg) {
            int rowl = wr + mi * 16 + quad * 4 + reg;
            int orow = SCATTER_OUT ? rs[rowl] : (m0 + rowl);
            OT* op = Out + (size_t)orow * ldo + n0;
            #pragma unroll
            for (int ni = 0; ni < NI; ++ni) {
                float v = acc[mi][ni][reg];
                if (GELU_ACT) v = gelu_fast(v);
                op[wc + ni * 16 + r] = (OT)v;
            }
        }
    }
}

// ---- dispatch 2: 768 blocks, 1/CU, per-CU schedule ~{2 ffn1 + 1 bypass}.
//   bid < 512: ffn1 256^2 (K=1024). XCD x=bid&7 owns mt 4x..4x+3; local
//              l=bid>>3: mt=4x+((l>>3)&3), nt=(l>>5)*8+(l&7) (supertiles).
//   bid >= 512: bypass 256x128 (K=1024), dispatched last (small jobs fill
//              the final scheduling round). id=bid-512: x=id&7, v=id>>3:
//              mt=4x+(v>>3), nt=v&7.
__global__ __launch_bounds__(512, 2) void gemm_mid(
    const __bf16* __restrict__ xb, const __bf16* __restrict__ w1b,
    __bf16* __restrict__ h, const __bf16* __restrict__ wbb,
    float* __restrict__ out,
    const int* __restrict__ sel_rows, const int* __restrict__ byp_rows)
{
    __shared__ __align__(16) __bf16 ringA[4][256 * 32];
    __shared__ __align__(16) __bf16 ringB[4][256 * 32];
    __shared__ int rs[256];
    int bid = blockIdx.x;
    if (bid < 512) {
        int x = bid & 7, l = bid >> 3;
        int mt = x * 4 + ((l >> 3) & 3);
        int nt = (l >> 5) * 8 + (l & 7);
        gemm256_core<256, true, false, true, __bf16>(
            xb, w1b, h, sel_rows, 1024, 0, 1024, 4096, mt, nt,
            &ringA[0][0], &ringB[0][0], rs);
    } else {
        int id = bid - 512;
        int x = id & 7, v = id >> 3;
        int mt = x * 4 + (v >> 3);
        int nt = v & 7;
        gemm256_core<128, true, true, false, float>(
            xb, wbb, out, byp_rows, 1024, 0, 1024, 1024, mt, nt,
            &ringA[0][0], &ringB[0][0], rs);
    }
}

// ---- dispatch 3: FFN2 as 256 uniform 256x128 jobs, FULL K=4096 (no
//      split-K, no reduce pass). 1/CU, single round. XCD x owns mt
//      4x..4x+3; l=bid>>3 (0..31): mt=4x+(l>>3), nt=l&7.
//      out[sel] = h@w2^T, scatter rows. Single fp32 MFMA accumulation
//      chain over k=0..4095.
__global__ __launch_bounds__(512, 2) void gemm_ffn2(
    const __bf16* __restrict__ h, const __bf16* __restrict__ w2b,
    float* __restrict__ out, const int* __restrict__ sel_rows)
{
    __shared__ __align__(16) __bf16 ringA[4][256 * 32];
    __shared__ __align__(16) __bf16 ringB[4][128 * 32];
    __shared__ int rs[256];
    int x = blockIdx.x & 7, l = blockIdx.x >> 3;
    int mt = x * 4 + (l >> 3);
    int nt = l & 7;
    gemm256_core<128, false, true, false, float>(
        h, w2b, out, sel_rows, 4096, 0, 4096, 1024, mt, nt,
        &ringA[0][0], &ringB[0][0], rs);
}

extern "C" void kernel_launch(void* const* d_in, const int* in_sizes, int n_in,
                              void* d_out, int out_size, void* d_ws, size_t ws_size,
                              hipStream_t stream) {
    (void)in_sizes; (void)n_in; (void)out_size; (void)ws_size;
    const float* x  = (const float*)d_in[0];
    const float* wr = (const float*)d_in[1];
    const float* wb = (const float*)d_in[2];
    const float* w1 = (const float*)d_in[3];
    const float* w2 = (const float*)d_in[4];
    float* out = (float*)d_out;

    const int B = 4, L = 4096, D = 1024, DFF = 4096, KSEL = 2048;
    const int M = B * KSEL;           // 8192
    const int NTOK = B * L;           // 16384

    size_t n_x = (size_t)NTOK * D, n_wb = (size_t)D * D;
    size_t n_w1 = (size_t)DFF * D, n_w2 = (size_t)D * DFF;

    char* ws = (char*)d_ws;
    float* scores = (float*)ws;            ws += sizeof(float) * (size_t)NTOK;
    int* sel_rows = (int*)ws;              ws += sizeof(int) * (size_t)M;
    int* byp_rows = (int*)ws;              ws += sizeof(int) * (size_t)M;
    uintptr_t up = ((uintptr_t)ws + 255) & ~(uintptr_t)255;
    __bf16* xb  = (__bf16*)up;             up += 2 * n_x;
    __bf16* wbb = (__bf16*)up;             up += 2 * n_wb;
    __bf16* w1b = (__bf16*)up;             up += 2 * n_w1;
    __bf16* w2b = (__bf16*)up;             up += 2 * n_w2;
    up = (up + 255) & ~(uintptr_t)255;
    __bf16* h   = (__bf16*)up;             // 8192 x 4096 bf16 = 64 MiB

    int nbr = NTOK / 4;                              // 4096 router blocks
    int ncv = (int)((n_wb + n_w1 + n_w2) / 8 / 256); // 4608 cvt blocks
    prep<<<nbr + ncv, 256, 0, stream>>>(
        x, wr, scores, xb, wb, w1, w2, wbb, w1b, w2b,
        nbr, (int)(n_wb / 8), (int)(n_w1 / 8), (int)(n_w2 / 8));
    topk_build<<<B, 1024, 0, stream>>>(scores, sel_rows, byp_rows);

    // FFN1 (512 jobs, 256^2) + bypass (256 jobs, 256x128) -> ~2.5 jobs/CU
    gemm_mid<<<768, 512, 0, stream>>>(xb, w1b, h, wbb, out, sel_rows, byp_rows);
    // FFN2: 256 uniform 256x128 jobs, full K=4096, 1/CU, no reduce pass
    gemm_ffn2<<<256, 512, 0, stream>>>(h, w2b, out, sel_rows);
}